// Round 8
// baseline (124.056 us; speedup 1.0000x reference)
//
#include <hip/hip_runtime.h>
#include <math.h>

#define NB 2048
#define DEPTH 8

// ws layout (float offsets)
#define FTAB_OFF    0        // sponge fused cs: 8*5*256*8 = 81920 floats
#define BF01_OFF    81920    // bf stages 0-1: 256*3*2 float4 = 6144 floats
#define BFF_OFF     88064    // bf fused (2,3)..(10,11): 5*256*8 = 10240 floats
#define ACT4_OFF    98304    // act table: 2048 float4 = 8192 floats
#define PHYSA_OFF   106496   // int2 per (d,t): mem scatter targets, 4096 ints
#define PHYSR_OFF   110592   // phys_recall[2048] int
#define PHYSO2_OFF  112640   // per-thread pre-gather [256*12] int
// total 115712 floats = 462848 bytes

// ---------------- single merged setup dispatch ----------------
__global__ void setup_kernel(const float* __restrict__ angles,
                             const float* __restrict__ bf_angles,
                             const float* __restrict__ act_bias,
                             const float* __restrict__ act_curv,
                             const int* __restrict__ recall_idx,
                             const int* __restrict__ out_mem_idx,
                             float* __restrict__ ws) {
    __shared__ int physL[4096];
    if (blockIdx.x < 200) {
        int id = blockIdx.x * 256 + threadIdx.x;
        if (id < 40960) {
            // sponge fused table: id = ((d*5+g)*256 + t)*4 + w ; quad a = t
            int w = id & 3, t = (id >> 2) & 255, dg = id >> 10;
            int d = dg / 5, g = dg - 5 * d;
            int a = t;
            int pair = (w == 0) ? a : (w == 1) ? (a + 256)
                     : (w == 2) ? (2 * a) : (2 * a + 1);
            int st = 2 * g + (w >> 1);
            float ang = angles[(d * 10 + st) * 512 + pair];
            float s, c; sincosf(ang, &s, &c);
            ws[FTAB_OFF + 2 * id]     = c;
            ws[FTAB_OFF + 2 * id + 1] = s;
        } else if (id < 44032) {
            // BF01: e = (t*3+i)*4 + w ; a = t+256i
            int e = id - 40960;
            int w = e & 3; int ti = e >> 2;
            int t = ti / 3; int i = ti - 3 * t;
            int a = t + 256 * i;
            int pair = (w == 0) ? a : (w == 1) ? (a + 768)
                     : (w == 2) ? (2 * a) : (2 * a + 1);
            int stage = (w < 2) ? 0 : 1;
            float ang = bf_angles[stage * 1536 + pair];
            float s, c; sincosf(ang, &s, &c);
            ws[BF01_OFF + 2 * e]     = c;
            ws[BF01_OFF + 2 * e + 1] = s;
        } else if (id < 49152) {
            // BFF: e = (f*256+t)*4 + w ; fused stages (2+2f, 3+2f)
            int e = id - 44032;
            int f = e >> 10; int rem = e & 1023; int t = rem >> 2; int w = rem & 3;
            int P;
            if (f == 0) P = 3 * t;
            else if (f < 4) { int k = 8 - 2 * f;
                              P = ((t >> (2 * f)) * (768 >> k)) + (t & ((256 >> k) - 1)); }
            else P = t;
            int pair = (w == 0) ? P : (w == 1) ? (P + 768)
                     : (w == 2) ? (2 * P) : (2 * P + 1);
            int stage = (w < 2) ? (2 + 2 * f) : (3 + 2 * f);
            float ang = bf_angles[stage * 1536 + pair];
            float s, c; sincosf(ang, &s, &c);
            ws[BFF_OFF + 2 * e]     = c;
            ws[BFF_OFF + 2 * e + 1] = s;
        } else if (id < 51200) {
            int ida = id - 49152;              // d*256 + k
            float cu = act_curv[ida];
            float c  = 0.5f * (cu + sqrtf(cu * cu + 1.0f));
            ((float4*)(ws + ACT4_OFF))[ida] =
                make_float4(act_bias[ida], c, 1.0f / c, 0.0f);
        }
    } else {
        // phys block: compacted mem slot allocation (2304 phys slots)
        int tid = threadIdx.x;
        for (int e = tid; e < 4096; e += 256) {
            int v = e, p;
            for (;;) {
                int d = v >> 9, j = v & 511;
                if (d == 0)  { p = j; break; }
                if (j < 256) { p = 256 + d * 256 + j; break; }
                v = recall_idx[(d - 1) * 256 + (j - 256)];
            }
            physL[e] = p;
        }
        __syncthreads();
        int* pa = (int*)(ws + PHYSA_OFF);
        for (int e = tid; e < 2048; e += 256) {
            int d = e >> 8, t = e & 255;
            pa[2 * e]     = physL[d * 512 + 2 * t];      // quad a = t: owns (2t, 2t+1)
            pa[2 * e + 1] = physL[d * 512 + 2 * t + 1];
        }
        int* pr = (int*)(ws + PHYSR_OFF);
        for (int e = tid; e < 2048; e += 256)
            pr[e] = physL[recall_idx[e]];
        int* po = (int*)(ws + PHYSO2_OFF);
        for (int e = tid; e < 3072; e += 256) {
            int tt = e / 12; int r = e - 12 * tt; int i = r >> 2; int k = r & 3;
            int a = tt + 256 * i;
            int tl2 = a >> 1, th2 = a & 1;
            int pos = tl2 + 1536 * th2 + 384 * k;
            po[e] = (pos < 2048) ? physL[out_mem_idx[pos]] : 2304 + (pos - 2048);
        }
    }
}

__device__ __forceinline__ float actf(float x, float c, float ic) {
    const float is2 = 0.70710678118654752f;
    float tt = 0.78539816339744831f * ic;
    float y0 = is2 * ic;
    float y1 = (is2 - 1.0f) * ic;
    float mid = ic * (is2 - __cosf(0.78539816339744831f + c * x));
    return x > tt ? (y0 + (x - tt)) : (x < -tt ? y1 : mid);
}

// bank-spread fold: XOR addr bits 5-6 into bits 3-4 (bijective, b64-safe)
__device__ __forceinline__ int fld(int s) { return s ^ (((s >> 5) & 3) << 3); }

// ---------------- main kernel: 2 rows per block ------------------------------------
__launch_bounds__(256, 4)
__global__ void sponge_kernel(const float* __restrict__ X,
                              const float* __restrict__ scales,
                              const float* __restrict__ ws,
                              float* __restrict__ out) {
    __shared__ float lds[8704];          // 34816 B -> 4 blocks/CU
    float* L0 = lds;                     // row A: memb [0,2304), exch [2304,4352)
    float* L1 = lds + 4352;              // row B
    const int t = threadIdx.x;
    const int rowA = blockIdx.x * 2;

    const float4* bf01  = (const float4*)(ws + BF01_OFF);
    const float4* bff   = (const float4*)(ws + BFF_OFF);
    const float4* act4  = (const float4*)(ws + ACT4_OFF);
    const int2* physA  = (const int2*)(ws + PHYSA_OFF);
    const int*  physr  = (const int*)(ws + PHYSR_OFF);
    const int*  physo2 = (const int*)(ws + PHYSO2_OFF);

    // quad a = t.  inputs: positions bq+128m, bq = (t>>1)+512*(t&1)
    const int bq = (t >> 1) + 512 * (t & 1);
    // exchange write bases (layout L + fold): pair (f0,f1) then (f2,f3) at +128
    const int W0 = fld(((2 * t) & 127) + 256 * (t >> 6));
    // exchange read base: rb + 256m
    const int rb = fld((t >> 1) + 128 * (t & 1));

    float hA0, hA1, hA2, hA3, hB0, hB1, hB2, hB3;
    {
        const float* Xr0 = X + (size_t)rowA * 1024;
        const float* Xr1 = Xr0 + 1024;
        float s0 = scales[bq],       s1 = scales[bq + 128];
        float s2 = scales[bq + 256], s3 = scales[bq + 384];
        hA0 = Xr0[bq] * s0; hA1 = Xr0[bq + 128] * s1;
        hA2 = Xr0[bq + 256] * s2; hA3 = Xr0[bq + 384] * s3;
        hB0 = Xr1[bq] * s0; hB1 = Xr1[bq + 128] * s1;
        hB2 = Xr1[bq + 256] * s2; hB3 = Xr1[bq + 384] * s3;
    }

    int woff = 2304, roff = 3328;
    const float4* ft = (const float4*)(ws + FTAB_OFF) + 2 * t;

#define DQUAD(cA, cB, i0, i1, i2, i3, F0, F1, F2, F3)                    \
    { float g0 =  (cA).x * (i0) + (cA).y * (i2);                         \
      float g2 = -(cA).y * (i0) + (cA).x * (i2);                         \
      float g1 =  (cA).z * (i1) + (cA).w * (i3);                         \
      float g3 = -(cA).w * (i1) + (cA).z * (i3);                         \
      F0 =  (cB).x * g0 + (cB).y * g1;                                   \
      F2 = -(cB).y * g0 + (cB).x * g1;                                   \
      F1 =  (cB).z * g2 + (cB).w * g3;                                   \
      F3 = -(cB).w * g2 + (cB).z * g3; }

    for (int d = 0; d < DEPTH; ++d) {
        for (int g = 0; g < 5; ++g) {
            float4 csA = ft[0], csB = ft[1]; ft += 512;
            float fA0, fA1, fA2, fA3, fB0, fB1, fB2, fB3;
            DQUAD(csA, csB, hA0, hA1, hA2, hA3, fA0, fA1, fA2, fA3);
            DQUAD(csA, csB, hB0, hB1, hB2, hB3, fB0, fB1, fB2, fB3);
            if (g < 4) {
                *(float2*)(L0 + woff + W0)       = make_float2(fA0, fA1);
                *(float2*)(L0 + woff + W0 + 128) = make_float2(fA2, fA3);
                *(float2*)(L1 + woff + W0)       = make_float2(fB0, fB1);
                *(float2*)(L1 + woff + W0 + 128) = make_float2(fB2, fB3);
                { int tmp = woff; woff = roff; roff = tmp; }
                __syncthreads();
                const float* e0 = L0 + roff + rb;
                const float* e1 = L1 + roff + rb;
                hA0 = e0[0]; hA1 = e0[256]; hA2 = e0[512]; hA3 = e0[768];
                hB0 = e1[0]; hB1 = e1[256]; hB2 = e1[512]; hB3 = e1[768];
            } else {
                // mem half (2t,2t+1): scatter from registers into compacted memb
                int2 pm = physA[d * 256 + t];
                L0[pm.x] = fA0; L0[pm.y] = fA1;
                L1[pm.x] = fB0; L1[pm.y] = fB1;
                // sponge half (512+2t, 512+2t+1) -> natural Z in the other buffer
                *(float2*)(L0 + woff + 2 * t) = make_float2(fA2, fA3);
                *(float2*)(L1 + woff + 2 * t) = make_float2(fB2, fB3);
                { int tmp = woff; woff = roff; roff = tmp; }
                // prefetch before barrier
                int r0 = 0, r1 = 0;
                float4 a0, a1, a2, a3;
                if (!(t & 1)) {
                    int kk = t >> 2;
                    a0 = act4[d * 256 + kk];
                    a1 = act4[d * 256 + kk + 64];
                    a2 = act4[d * 256 + kk + 128];
                    a3 = act4[d * 256 + kk + 192];
                } else {
                    r0 = physr[d * 256 + (t >> 1)];
                    r1 = physr[d * 256 + (t >> 1) + 128];
                }
                __syncthreads();         // Z + mem scatter visible
                const float* Z0 = L0 + roff;
                const float* Z1 = L1 + roff;
                if (!(t & 1)) {
                    // act region: positions bq+128m all < 512
                    int kk = t >> 2;
                    float sgn = (t & 2) ? -1.0f : 1.0f;
                    hA0 = actf(sgn * (Z0[kk]       + a0.x), a0.y, a0.z);
                    hA1 = actf(sgn * (Z0[kk + 64]  + a1.x), a1.y, a1.z);
                    hA2 = actf(sgn * (Z0[kk + 128] + a2.x), a2.y, a2.z);
                    hA3 = actf(sgn * (Z0[kk + 192] + a3.x), a3.y, a3.z);
                    hB0 = actf(sgn * (Z1[kk]       + a0.x), a0.y, a0.z);
                    hB1 = actf(sgn * (Z1[kk + 64]  + a1.x), a1.y, a1.z);
                    hB2 = actf(sgn * (Z1[kk + 128] + a2.x), a2.y, a2.z);
                    hB3 = actf(sgn * (Z1[kk + 192] + a3.x), a3.y, a3.z);
                } else {
                    // keep (m=0,1) + recall (m=2,3)
                    int j = t >> 1;
                    hA0 = Z0[256 + j]; hA1 = Z0[384 + j];
                    hB0 = Z1[256 + j]; hB1 = Z1[384 + j];
                    hA2 = L0[r0]; hA3 = L0[r1];
                    hB2 = L1[r0]; hB3 = L1[r1];
                }
            }
        }
    }

    // ---- stage sponge into natural layout at [2304, 3328) ----
    L0[2304 + bq] = hA0; L0[2304 + bq + 128] = hA1;
    L0[2304 + bq + 256] = hA2; L0[2304 + bq + 384] = hA3;
    L1[2304 + bq] = hB0; L1[2304 + bq + 128] = hB1;
    L1[2304 + bq + 256] = hB2; L1[2304 + bq + 384] = hB3;
    __syncthreads();

    // ---- gather pre into 24 named scalars ----
    float vA0, vA1, vA2, vA3, vA4, vA5, vA6, vA7, vA8, vA9, vA10, vA11;
    float vB0, vB1, vB2, vB3, vB4, vB5, vB6, vB7, vB8, vB9, vB10, vB11;
    {
        int4 pg = ((const int4*)(physo2 + t * 12))[0];
        vA0 = L0[pg.x]; vA1 = L0[pg.y]; vA2 = L0[pg.z]; vA3 = L0[pg.w];
        vB0 = L1[pg.x]; vB1 = L1[pg.y]; vB2 = L1[pg.z]; vB3 = L1[pg.w];
        pg = ((const int4*)(physo2 + t * 12))[1];
        vA4 = L0[pg.x]; vA5 = L0[pg.y]; vA6 = L0[pg.z]; vA7 = L0[pg.w];
        vB4 = L1[pg.x]; vB5 = L1[pg.y]; vB6 = L1[pg.z]; vB7 = L1[pg.w];
        pg = ((const int4*)(physo2 + t * 12))[2];
        vA8 = L0[pg.x]; vA9 = L0[pg.y]; vA10 = L0[pg.z]; vA11 = L0[pg.w];
        vB8 = L1[pg.x]; vB9 = L1[pg.y]; vB10 = L1[pg.z]; vB11 = L1[pg.w];
    }
    __syncthreads();                     // all reads done before overwrite

    // ---- fused stages (0,1) in registers ----
#define BF01_STEP(i, qA0, qA1, qA2, qA3, qB0, qB1, qB2, qB3)                        \
    {                                                                               \
        float4 c01 = bf01[(t * 3 + (i)) * 2];                                       \
        float4 c23 = bf01[(t * 3 + (i)) * 2 + 1];                                   \
        float y0, y1, y2, y3;                                                       \
        DQUAD(c01, c23, qA0, qA1, qA2, qA3, y0, y1, y2, y3);                        \
        *(float2*)(L0 + 2 * t + 512 * (i))        = make_float2(y0, y1);            \
        *(float2*)(L0 + 2 * t + 512 * (i) + 1536) = make_float2(y2, y3);            \
        DQUAD(c01, c23, qB0, qB1, qB2, qB3, y0, y1, y2, y3);                        \
        *(float2*)(L1 + 2 * t + 512 * (i))        = make_float2(y0, y1);            \
        *(float2*)(L1 + 2 * t + 512 * (i) + 1536) = make_float2(y2, y3);            \
    }
    BF01_STEP(0, vA0, vA1, vA2, vA3, vB0, vB1, vB2, vB3)
    BF01_STEP(1, vA4, vA5, vA6, vA7, vB4, vB5, vB6, vB7)
    BF01_STEP(2, vA8, vA9, vA10, vA11, vB8, vB9, vB10, vB11)
#undef BF01_STEP
    __syncthreads();

    // ---- fused pruned double-stages (2,3) (4,5) (6,7) (8,9) ----
#pragma unroll
    for (int f = 0; f < 4; ++f) {
        int P;
        if (f == 0) P = 3 * t;
        else { const int k = 8 - 2 * f;
               P = ((t >> (2 * f)) * (768 >> k)) + (t & ((256 >> k) - 1)); }
        int base = (P >> 1) + (P & 1) * 1536;
        float4 csS = bff[(f * 256 + t) * 2];
        float4 csT = bff[(f * 256 + t) * 2 + 1];
        float xA1p = L0[base], xA1q = L0[base + 384];
        float xA2p = L0[base + 768], xA2q = L0[base + 1152];
        float xB1p = L1[base], xB1q = L1[base + 384];
        float xB2p = L1[base + 768], xB2q = L1[base + 1152];
        float o1P =  csS.x * xA1p + csS.y * xA2p;
        float o2P = -csS.y * xA1p + csS.x * xA2p;
        float o1Q =  csS.z * xA1q + csS.w * xA2q;
        float o2Q = -csS.w * xA1q + csS.z * xA2q;
        float yA0 =  csT.x * o1P + csT.y * o1Q;
        float yA2 = -csT.y * o1P + csT.x * o1Q;
        float yA1 =  csT.z * o2P + csT.w * o2Q;
        float yA3 = -csT.w * o2P + csT.z * o2Q;
        o1P =  csS.x * xB1p + csS.y * xB2p;
        o2P = -csS.y * xB1p + csS.x * xB2p;
        o1Q =  csS.z * xB1q + csS.w * xB2q;
        o2Q = -csS.w * xB1q + csS.z * xB2q;
        float yB0 =  csT.x * o1P + csT.y * o1Q;
        float yB2 = -csT.y * o1P + csT.x * o1Q;
        float yB1 =  csT.z * o2P + csT.w * o2Q;
        float yB3 = -csT.w * o2P + csT.z * o2Q;
        __syncthreads();
        *(float2*)(L0 + 2 * P)        = make_float2(yA0, yA1);
        *(float2*)(L0 + 2 * P + 1536) = make_float2(yA2, yA3);
        *(float2*)(L1 + 2 * P)        = make_float2(yB0, yB1);
        *(float2*)(L1 + 2 * P + 1536) = make_float2(yB2, yB3);
        __syncthreads();
    }

    // ---- fused (10,11) + output store ----
    {
        int base = (t >> 1) + (t & 1) * 1536;
        float4 csS = bff[(4 * 256 + t) * 2];
        float4 csT = bff[(4 * 256 + t) * 2 + 1];
        float x1p = L0[base], x1q = L0[base + 384];
        float x2p = L0[base + 768], x2q = L0[base + 1152];
        float o1P =  csS.x * x1p + csS.y * x2p;
        float o2P = -csS.y * x1p + csS.x * x2p;
        float o1Q =  csS.z * x1q + csS.w * x2q;
        float o2Q = -csS.w * x1q + csS.z * x2q;
        *(float2*)(out + (size_t)rowA * 512 + 2 * t) =
            make_float2(csT.x * o1P + csT.y * o1Q, csT.z * o2P + csT.w * o2Q);
        x1p = L1[base]; x1q = L1[base + 384];
        x2p = L1[base + 768]; x2q = L1[base + 1152];
        o1P =  csS.x * x1p + csS.y * x2p;
        o2P = -csS.y * x1p + csS.x * x2p;
        o1Q =  csS.z * x1q + csS.w * x2q;
        o2Q = -csS.w * x1q + csS.z * x2q;
        *(float2*)(out + (size_t)(rowA + 1) * 512 + 2 * t) =
            make_float2(csT.x * o1P + csT.y * o1Q, csT.z * o2P + csT.w * o2Q);
    }
#undef DQUAD
}

extern "C" void kernel_launch(void* const* d_in, const int* in_sizes, int n_in,
                              void* d_out, int out_size, void* d_ws, size_t ws_size,
                              hipStream_t stream) {
    const float* X          = (const float*)d_in[0];
    const float* scales     = (const float*)d_in[1];
    const float* angles     = (const float*)d_in[2];
    const float* act_bias   = (const float*)d_in[3];
    // d_in[4] act_activation — unused by the reference
    const float* act_curv   = (const float*)d_in[5];
    const float* bf_angles  = (const float*)d_in[6];
    // d_in[7] shuffle_perm — structural perfect shuffle, hardcoded
    const int*   recall_idx  = (const int*)d_in[8];
    const int*   out_mem_idx = (const int*)d_in[9];
    // d_in[10] bf_perm — structural perfect shuffle, hardcoded

    float* ws = (float*)d_ws;   // 462848 bytes used

    setup_kernel<<<201, 256, 0, stream>>>(angles, bf_angles, act_bias, act_curv,
                                          recall_idx, out_mem_idx, ws);
    sponge_kernel<<<NB / 2, 256, 0, stream>>>(X, scales, ws, (float*)d_out);
}

// Round 10
// 119.381 us; speedup vs baseline: 1.0392x; 1.0392x over previous
//
#include <hip/hip_runtime.h>
#include <math.h>

#define NB 2048
#define DEPTH 8

// ws layout (float offsets)
#define FTAB_OFF    0        // sponge fused cs: 8*5*256*8 = 81920 floats
#define BF01_OFF    81920    // bf stages 0-1: 256*3*2 float4 = 6144 floats
#define BFF_OFF     88064    // bf fused (2,3)..(10,11): 5*256*8 = 10240 floats
#define ACT4_OFF    98304    // act table: 2048 float4 = 8192 floats
#define PHYSA_OFF   106496   // int2 per (d,t): mem scatter targets, 4096 ints
#define PHYSR_OFF   110592   // phys_recall[2048] int
#define PHYSO2_OFF  112640   // per-thread pre-gather [256*12] int
// total 115712 floats = 462848 bytes

// ---------------- single merged setup dispatch ----------------
__global__ void setup_kernel(const float* __restrict__ angles,
                             const float* __restrict__ bf_angles,
                             const float* __restrict__ act_bias,
                             const float* __restrict__ act_curv,
                             const int* __restrict__ recall_idx,
                             const int* __restrict__ out_mem_idx,
                             float* __restrict__ ws) {
    __shared__ int physL[4096];
    if (blockIdx.x < 200) {
        int id = blockIdx.x * 256 + threadIdx.x;
        if (id < 40960) {
            // sponge fused table: id = ((d*5+g)*256 + t)*4 + w ; quad a = 2*(t&127)+(t>>7)
            int w = id & 3, t = (id >> 2) & 255, dg = id >> 10;
            int d = dg / 5, g = dg - 5 * d;
            int a = 2 * (t & 127) + (t >> 7);
            int pair = (w == 0) ? a : (w == 1) ? (a + 256)
                     : (w == 2) ? (2 * a) : (2 * a + 1);
            int st = 2 * g + (w >> 1);
            float ang = angles[(d * 10 + st) * 512 + pair];
            float s, c; sincosf(ang, &s, &c);
            ws[FTAB_OFF + 2 * id]     = c;
            ws[FTAB_OFF + 2 * id + 1] = s;
        } else if (id < 44032) {
            // BF01: e = (t*3+i)*4 + w ; a = t+256i
            int e = id - 40960;
            int w = e & 3; int ti = e >> 2;
            int t = ti / 3; int i = ti - 3 * t;
            int a = t + 256 * i;
            int pair = (w == 0) ? a : (w == 1) ? (a + 768)
                     : (w == 2) ? (2 * a) : (2 * a + 1);
            int stage = (w < 2) ? 0 : 1;
            float ang = bf_angles[stage * 1536 + pair];
            float s, c; sincosf(ang, &s, &c);
            ws[BF01_OFF + 2 * e]     = c;
            ws[BF01_OFF + 2 * e + 1] = s;
        } else if (id < 49152) {
            // BFF: e = (f*256+t)*4 + w ; fused stages (2+2f, 3+2f)
            int e = id - 44032;
            int f = e >> 10; int rem = e & 1023; int t = rem >> 2; int w = rem & 3;
            int P;
            if (f == 0) P = 3 * t;
            else if (f < 4) { int k = 8 - 2 * f;
                              P = ((t >> (2 * f)) * (768 >> k)) + (t & ((256 >> k) - 1)); }
            else P = t;
            int pair = (w == 0) ? P : (w == 1) ? (P + 768)
                     : (w == 2) ? (2 * P) : (2 * P + 1);
            int stage = (w < 2) ? (2 + 2 * f) : (3 + 2 * f);
            float ang = bf_angles[stage * 1536 + pair];
            float s, c; sincosf(ang, &s, &c);
            ws[BFF_OFF + 2 * e]     = c;
            ws[BFF_OFF + 2 * e + 1] = s;
        } else if (id < 51200) {
            int ida = id - 49152;              // d*256 + k
            float cu = act_curv[ida];
            float c  = 0.5f * (cu + sqrtf(cu * cu + 1.0f));
            ((float4*)(ws + ACT4_OFF))[ida] =
                make_float4(act_bias[ida], c, 1.0f / c, 0.0f);
        }
    } else {
        // phys block: compacted mem slot allocation (2304 phys slots)
        int tid = threadIdx.x;
        for (int e = tid; e < 4096; e += 256) {
            int v = e, p;
            for (;;) {
                int d = v >> 9, j = v & 511;
                if (d == 0)  { p = j; break; }
                if (j < 256) { p = 256 + d * 256 + j; break; }
                v = recall_idx[(d - 1) * 256 + (j - 256)];
            }
            physL[e] = p;
        }
        __syncthreads();
        int* pa = (int*)(ws + PHYSA_OFF);
        for (int e = tid; e < 2048; e += 256) {
            int d = e >> 8, t = e & 255;
            int a = 2 * (t & 127) + (t >> 7);
            pa[2 * e]     = physL[d * 512 + 2 * a];
            pa[2 * e + 1] = physL[d * 512 + 2 * a + 1];
        }
        int* pr = (int*)(ws + PHYSR_OFF);
        for (int e = tid; e < 2048; e += 256)
            pr[e] = physL[recall_idx[e]];
        int* po = (int*)(ws + PHYSO2_OFF);
        for (int e = tid; e < 3072; e += 256) {
            int tt = e / 12; int r = e - 12 * tt; int i = r >> 2; int k = r & 3;
            int a = tt + 256 * i;
            int tl2 = a >> 1, th2 = a & 1;
            int pos = tl2 + 1536 * th2 + 384 * k;
            po[e] = (pos < 2048) ? physL[out_mem_idx[pos]] : 2304 + (pos - 2048);
        }
    }
}

__device__ __forceinline__ float actf(float x, float c, float ic) {
    const float is2 = 0.70710678118654752f;
    float tt = 0.78539816339744831f * ic;
    float y0 = is2 * ic;
    float y1 = (is2 - 1.0f) * ic;
    float mid = ic * (is2 - __cosf(0.78539816339744831f + c * x));
    return x > tt ? (y0 + (x - tt)) : (x < -tt ? y1 : mid);
}

// ---------------- main kernel: 2 rows per block ------------------------------------
__launch_bounds__(256, 4)
__global__ void sponge_kernel(const float* __restrict__ X,
                              const float* __restrict__ scales,
                              const float* __restrict__ ws,
                              float* __restrict__ out) {
    __shared__ float lds[8704];          // 34816 B -> 4 blocks/CU
    float* L0 = lds;                     // row A: memb [0,2304), exch [2304,4352)
    float* L1 = lds + 4352;              // row B
    const int t = threadIdx.x;
    const int rowA = blockIdx.x * 2;

    const float4* bf01  = (const float4*)(ws + BF01_OFF);
    const float4* bff   = (const float4*)(ws + BFF_OFF);
    const float4* act4  = (const float4*)(ws + ACT4_OFF);
    const int2* physA  = (const int2*)(ws + PHYSA_OFF);
    const int*  physr  = (const int*)(ws + PHYSR_OFF);
    const int*  physo2 = (const int*)(ws + PHYSO2_OFF);

    const int tl = t & 127, th = t >> 7;
    const int b  = tl + th * 512;        // holdings {b+128m}; quad a = 2tl+th
    // conflict-free exchange layout A (bit permutation):
    //   A0=p0, A1..A4=p2..p5, A5=p1, A6..A9=p6..p9
    const int Wb = 2 * (tl & 15) + 32 * th + 64 * (tl >> 4);    // writes: Wb, Wb+512
    const int Rb = (tl & 1) + 2 * ((tl >> 2) & 15) + 32 * ((tl >> 1) & 1)
                 + 64 * (tl >> 6) + 512 * th;                   // reads: Rb + 128m
    const int u  = t - 128;

    float hA0, hA1, hA2, hA3, hB0, hB1, hB2, hB3;
    {
        const float* Xr0 = X + (size_t)rowA * 1024;
        const float* Xr1 = Xr0 + 1024;
        float s0 = scales[b],       s1 = scales[b + 128];
        float s2 = scales[b + 256], s3 = scales[b + 384];
        hA0 = Xr0[b] * s0; hA1 = Xr0[b + 128] * s1;
        hA2 = Xr0[b + 256] * s2; hA3 = Xr0[b + 384] * s3;
        hB0 = Xr1[b] * s0; hB1 = Xr1[b + 128] * s1;
        hB2 = Xr1[b + 256] * s2; hB3 = Xr1[b + 384] * s3;
    }

    int woff = 2304, roff = 3328;
    const float4* ft = (const float4*)(ws + FTAB_OFF) + 2 * t;

#define DQUAD(cA, cB, i0, i1, i2, i3, F0, F1, F2, F3)                    \
    { float g0 =  (cA).x * (i0) + (cA).y * (i2);                         \
      float g2 = -(cA).y * (i0) + (cA).x * (i2);                         \
      float g1 =  (cA).z * (i1) + (cA).w * (i3);                         \
      float g3 = -(cA).w * (i1) + (cA).z * (i3);                         \
      F0 =  (cB).x * g0 + (cB).y * g1;                                   \
      F2 = -(cB).y * g0 + (cB).x * g1;                                   \
      F1 =  (cB).z * g2 + (cB).w * g3;                                   \
      F3 = -(cB).w * g2 + (cB).z * g3; }

    for (int d = 0; d < DEPTH; ++d) {
        for (int g = 0; g < 5; ++g) {
            float4 csA = ft[0], csB = ft[1]; ft += 512;
            float fA0, fA1, fA2, fA3, fB0, fB1, fB2, fB3;
            DQUAD(csA, csB, hA0, hA1, hA2, hA3, fA0, fA1, fA2, fA3);
            DQUAD(csA, csB, hB0, hB1, hB2, hB3, fB0, fB1, fB2, fB3);
            if (g < 4) {
                *(float2*)(L0 + woff + Wb)       = make_float2(fA0, fA1);
                *(float2*)(L0 + woff + Wb + 512) = make_float2(fA2, fA3);
                *(float2*)(L1 + woff + Wb)       = make_float2(fB0, fB1);
                *(float2*)(L1 + woff + Wb + 512) = make_float2(fB2, fB3);
                { int tmp = woff; woff = roff; roff = tmp; }
                __syncthreads();
                const float* e0 = L0 + roff + Rb;
                const float* e1 = L1 + roff + Rb;
                hA0 = e0[0]; hA1 = e0[128]; hA2 = e0[256]; hA3 = e0[384];
                hB0 = e1[0]; hB1 = e1[128]; hB2 = e1[256]; hB3 = e1[384];
            } else {
                // mem half (2a, 2a+1): scatter from registers into compacted memb
                int2 pm = physA[d * 256 + t];
                L0[pm.x] = fA0; L0[pm.y] = fA1;
                L1[pm.x] = fB0; L1[pm.y] = fB1;
                // sponge half (2a+512, 2a+513) -> natural Z in the write buffer
                *(float2*)(L0 + woff + 4 * tl + 2 * th) = make_float2(fA2, fA3);
                *(float2*)(L1 + woff + 4 * tl + 2 * th) = make_float2(fB2, fB3);
                { int tmp = woff; woff = roff; roff = tmp; }
                // prefetch before barrier (wave-aligned split: no intra-wave divergence)
                int r0 = 0, r1 = 0;
                float4 a0, a1, a2, a3;
                if (t < 128) {
                    int k0 = t >> 1;
                    a0 = act4[d * 256 + k0];
                    a1 = act4[d * 256 + k0 + 64];
                    a2 = act4[d * 256 + k0 + 128];
                    a3 = act4[d * 256 + k0 + 192];
                } else {
                    r0 = physr[d * 256 + u];
                    r1 = physr[d * 256 + u + 128];
                }
                __syncthreads();         // Z + mem scatter visible
                const float* Z0 = L0 + roff;
                const float* Z1 = L1 + roff;
                if (t < 128) {
                    int k0 = t >> 1;
                    float sgn = (t & 1) ? -1.0f : 1.0f;
                    hA0 = actf(sgn * (Z0[k0]       + a0.x), a0.y, a0.z);
                    hA1 = actf(sgn * (Z0[k0 + 64]  + a1.x), a1.y, a1.z);
                    hA2 = actf(sgn * (Z0[k0 + 128] + a2.x), a2.y, a2.z);
                    hA3 = actf(sgn * (Z0[k0 + 192] + a3.x), a3.y, a3.z);
                    hB0 = actf(sgn * (Z1[k0]       + a0.x), a0.y, a0.z);
                    hB1 = actf(sgn * (Z1[k0 + 64]  + a1.x), a1.y, a1.z);
                    hB2 = actf(sgn * (Z1[k0 + 128] + a2.x), a2.y, a2.z);
                    hB3 = actf(sgn * (Z1[k0 + 192] + a3.x), a3.y, a3.z);
                } else {
                    // keep: positions {512+u, 640+u} -> z[768+u], z[896+u] -> Z[256+u], Z[384+u]
                    hA0 = Z0[256 + u]; hA1 = Z0[384 + u];
                    hB0 = Z1[256 + u]; hB1 = Z1[384 + u];
                    hA2 = L0[r0]; hA3 = L0[r1];
                    hB2 = L1[r0]; hB3 = L1[r1];
                }
            }
        }
    }

    // ---- stage sponge into natural layout at [2304, 3328) ----
    L0[2304 + b] = hA0; L0[2304 + b + 128] = hA1;
    L0[2304 + b + 256] = hA2; L0[2304 + b + 384] = hA3;
    L1[2304 + b] = hB0; L1[2304 + b + 128] = hB1;
    L1[2304 + b + 256] = hB2; L1[2304 + b + 384] = hB3;
    __syncthreads();

    // ---- gather pre into 24 named scalars ----
    float vA0, vA1, vA2, vA3, vA4, vA5, vA6, vA7, vA8, vA9, vA10, vA11;
    float vB0, vB1, vB2, vB3, vB4, vB5, vB6, vB7, vB8, vB9, vB10, vB11;
    {
        int4 pg = ((const int4*)(physo2 + t * 12))[0];
        vA0 = L0[pg.x]; vA1 = L0[pg.y]; vA2 = L0[pg.z]; vA3 = L0[pg.w];
        vB0 = L1[pg.x]; vB1 = L1[pg.y]; vB2 = L1[pg.z]; vB3 = L1[pg.w];
        pg = ((const int4*)(physo2 + t * 12))[1];
        vA4 = L0[pg.x]; vA5 = L0[pg.y]; vA6 = L0[pg.z]; vA7 = L0[pg.w];
        vB4 = L1[pg.x]; vB5 = L1[pg.y]; vB6 = L1[pg.z]; vB7 = L1[pg.w];
        pg = ((const int4*)(physo2 + t * 12))[2];
        vA8 = L0[pg.x]; vA9 = L0[pg.y]; vA10 = L0[pg.z]; vA11 = L0[pg.w];
        vB8 = L1[pg.x]; vB9 = L1[pg.y]; vB10 = L1[pg.z]; vB11 = L1[pg.w];
    }
    __syncthreads();                     // all reads done before overwrite

    // ---- fused stages (0,1) in registers ----
#define BF01_STEP(i, qA0, qA1, qA2, qA3, qB0, qB1, qB2, qB3)                        \
    {                                                                               \
        float4 c01 = bf01[(t * 3 + (i)) * 2];                                       \
        float4 c23 = bf01[(t * 3 + (i)) * 2 + 1];                                   \
        float y0, y1, y2, y3;                                                       \
        DQUAD(c01, c23, qA0, qA1, qA2, qA3, y0, y1, y2, y3);                        \
        *(float2*)(L0 + 2 * t + 512 * (i))        = make_float2(y0, y1);            \
        *(float2*)(L0 + 2 * t + 512 * (i) + 1536) = make_float2(y2, y3);            \
        DQUAD(c01, c23, qB0, qB1, qB2, qB3, y0, y1, y2, y3);                        \
        *(float2*)(L1 + 2 * t + 512 * (i))        = make_float2(y0, y1);            \
        *(float2*)(L1 + 2 * t + 512 * (i) + 1536) = make_float2(y2, y3);            \
    }
    BF01_STEP(0, vA0, vA1, vA2, vA3, vB0, vB1, vB2, vB3)
    BF01_STEP(1, vA4, vA5, vA6, vA7, vB4, vB5, vB6, vB7)
    BF01_STEP(2, vA8, vA9, vA10, vA11, vB8, vB9, vB10, vB11)
#undef BF01_STEP
    __syncthreads();

    // ---- fused pruned double-stages (2,3) (4,5) (6,7) (8,9) ----
#pragma unroll
    for (int f = 0; f < 4; ++f) {
        int P;
        if (f == 0) P = 3 * t;
        else { const int k = 8 - 2 * f;
               P = ((t >> (2 * f)) * (768 >> k)) + (t & ((256 >> k) - 1)); }
        int base = (P >> 1) + (P & 1) * 1536;
        float4 csS = bff[(f * 256 + t) * 2];
        float4 csT = bff[(f * 256 + t) * 2 + 1];
        float xA1p = L0[base], xA1q = L0[base + 384];
        float xA2p = L0[base + 768], xA2q = L0[base + 1152];
        float xB1p = L1[base], xB1q = L1[base + 384];
        float xB2p = L1[base + 768], xB2q = L1[base + 1152];
        float o1P =  csS.x * xA1p + csS.y * xA2p;
        float o2P = -csS.y * xA1p + csS.x * xA2p;
        float o1Q =  csS.z * xA1q + csS.w * xA2q;
        float o2Q = -csS.w * xA1q + csS.z * xA2q;
        float yA0 =  csT.x * o1P + csT.y * o1Q;
        float yA2 = -csT.y * o1P + csT.x * o1Q;
        float yA1 =  csT.z * o2P + csT.w * o2Q;
        float yA3 = -csT.w * o2P + csT.z * o2Q;
        o1P =  csS.x * xB1p + csS.y * xB2p;
        o2P = -csS.y * xB1p + csS.x * xB2p;
        o1Q =  csS.z * xB1q + csS.w * xB2q;
        o2Q = -csS.w * xB1q + csS.z * xB2q;
        float yB0 =  csT.x * o1P + csT.y * o1Q;
        float yB2 = -csT.y * o1P + csT.x * o1Q;
        float yB1 =  csT.z * o2P + csT.w * o2Q;
        float yB3 = -csT.w * o2P + csT.z * o2Q;
        __syncthreads();
        *(float2*)(L0 + 2 * P)        = make_float2(yA0, yA1);
        *(float2*)(L0 + 2 * P + 1536) = make_float2(yA2, yA3);
        *(float2*)(L1 + 2 * P)        = make_float2(yB0, yB1);
        *(float2*)(L1 + 2 * P + 1536) = make_float2(yB2, yB3);
        __syncthreads();
    }

    // ---- fused (10,11) + output store ----
    {
        int base = (t >> 1) + (t & 1) * 1536;
        float4 csS = bff[(4 * 256 + t) * 2];
        float4 csT = bff[(4 * 256 + t) * 2 + 1];
        float x1p = L0[base], x1q = L0[base + 384];
        float x2p = L0[base + 768], x2q = L0[base + 1152];
        float o1P =  csS.x * x1p + csS.y * x2p;
        float o2P = -csS.y * x1p + csS.x * x2p;
        float o1Q =  csS.z * x1q + csS.w * x2q;
        float o2Q = -csS.w * x1q + csS.z * x2q;
        *(float2*)(out + (size_t)rowA * 512 + 2 * t) =
            make_float2(csT.x * o1P + csT.y * o1Q, csT.z * o2P + csT.w * o2Q);
        x1p = L1[base]; x1q = L1[base + 384];
        x2p = L1[base + 768]; x2q = L1[base + 1152];
        o1P =  csS.x * x1p + csS.y * x2p;
        o2P = -csS.y * x1p + csS.x * x2p;
        o1Q =  csS.z * x1q + csS.w * x2q;
        o2Q = -csS.w * x1q + csS.z * x2q;
        *(float2*)(out + (size_t)(rowA + 1) * 512 + 2 * t) =
            make_float2(csT.x * o1P + csT.y * o1Q, csT.z * o2P + csT.w * o2Q);
    }
#undef DQUAD
}

extern "C" void kernel_launch(void* const* d_in, const int* in_sizes, int n_in,
                              void* d_out, int out_size, void* d_ws, size_t ws_size,
                              hipStream_t stream) {
    const float* X          = (const float*)d_in[0];
    const float* scales     = (const float*)d_in[1];
    const float* angles     = (const float*)d_in[2];
    const float* act_bias   = (const float*)d_in[3];
    // d_in[4] act_activation — unused by the reference
    const float* act_curv   = (const float*)d_in[5];
    const float* bf_angles  = (const float*)d_in[6];
    // d_in[7] shuffle_perm — structural perfect shuffle, hardcoded
    const int*   recall_idx  = (const int*)d_in[8];
    const int*   out_mem_idx = (const int*)d_in[9];
    // d_in[10] bf_perm — structural perfect shuffle, hardcoded

    float* ws = (float*)d_ws;   // 462848 bytes used

    setup_kernel<<<201, 256, 0, stream>>>(angles, bf_angles, act_bias, act_curv,
                                          recall_idx, out_mem_idx, ws);
    sponge_kernel<<<NB / 2, 256, 0, stream>>>(X, scales, ws, (float*)d_out);
}

// Round 11
// 118.060 us; speedup vs baseline: 1.0508x; 1.0112x over previous
//
#include <hip/hip_runtime.h>
#include <math.h>

#define NB 2048
#define DEPTH 8

// ws layout (float offsets)
#define FTAB_OFF    0        // sponge fused cs: 8*5*256*8 = 81920 floats
#define BF01_OFF    81920    // bf stages 0-1: 256*3*2 float4 = 6144 floats
#define BFF_OFF     88064    // bf fused (2,3)..(10,11): 5*256*8 = 10240 floats
#define ACT4_OFF    98304    // act table: 2048 float4 = 8192 floats
#define PHYSA_OFF   106496   // int2 per (d,t): interleaved mem scatter addrs, 4096 ints
#define PHYSR_OFF   110592   // interleaved recall addrs [2048] int
#define PHYSO2_OFF  112640   // per-thread pre-gather absolute addrs [256*12] int
// total 115712 floats = 462848 bytes

// LDS map (floats): memb interleaved [0,4608); exch buf0 [4608,6656); buf1 [6656,8704)
#define MB0 4608
#define MB1 6656

// ---------------- single merged setup dispatch ----------------
__global__ void setup_kernel(const float* __restrict__ angles,
                             const float* __restrict__ bf_angles,
                             const float* __restrict__ act_bias,
                             const float* __restrict__ act_curv,
                             const int* __restrict__ recall_idx,
                             const int* __restrict__ out_mem_idx,
                             float* __restrict__ ws) {
    __shared__ int physL[4096];
    if (blockIdx.x < 200) {
        int id = blockIdx.x * 256 + threadIdx.x;
        if (id < 40960) {
            // sponge fused table: id = ((d*5+g)*256 + t)*4 + w ; quad a = 2*(t&127)+(t>>7)
            int w = id & 3, t = (id >> 2) & 255, dg = id >> 10;
            int d = dg / 5, g = dg - 5 * d;
            int a = 2 * (t & 127) + (t >> 7);
            int pair = (w == 0) ? a : (w == 1) ? (a + 256)
                     : (w == 2) ? (2 * a) : (2 * a + 1);
            int st = 2 * g + (w >> 1);
            float ang = angles[(d * 10 + st) * 512 + pair];
            float s, c; __sincosf(ang, &s, &c);
            ws[FTAB_OFF + 2 * id]     = c;
            ws[FTAB_OFF + 2 * id + 1] = s;
        } else if (id < 44032) {
            // BF01: e = (t*3+i)*4 + w ; a = t+256i
            int e = id - 40960;
            int w = e & 3; int ti = e >> 2;
            int t = ti / 3; int i = ti - 3 * t;
            int a = t + 256 * i;
            int pair = (w == 0) ? a : (w == 1) ? (a + 768)
                     : (w == 2) ? (2 * a) : (2 * a + 1);
            int stage = (w < 2) ? 0 : 1;
            float ang = bf_angles[stage * 1536 + pair];
            float s, c; __sincosf(ang, &s, &c);
            ws[BF01_OFF + 2 * e]     = c;
            ws[BF01_OFF + 2 * e + 1] = s;
        } else if (id < 49152) {
            // BFF: e = (f*256+t)*4 + w ; fused stages (2+2f, 3+2f)
            int e = id - 44032;
            int f = e >> 10; int rem = e & 1023; int t = rem >> 2; int w = rem & 3;
            int P;
            if (f == 0) P = 3 * t;
            else if (f < 4) { int k = 8 - 2 * f;
                              P = ((t >> (2 * f)) * (768 >> k)) + (t & ((256 >> k) - 1)); }
            else P = t;
            int pair = (w == 0) ? P : (w == 1) ? (P + 768)
                     : (w == 2) ? (2 * P) : (2 * P + 1);
            int stage = (w < 2) ? (2 + 2 * f) : (3 + 2 * f);
            float ang = bf_angles[stage * 1536 + pair];
            float s, c; __sincosf(ang, &s, &c);
            ws[BFF_OFF + 2 * e]     = c;
            ws[BFF_OFF + 2 * e + 1] = s;
        } else if (id < 51200) {
            int ida = id - 49152;              // d*256 + k
            float cu = act_curv[ida];
            float c  = 0.5f * (cu + sqrtf(cu * cu + 1.0f));
            ((float4*)(ws + ACT4_OFF))[ida] =
                make_float4(act_bias[ida], c, 1.0f / c, 0.0f);
        }
    } else {
        // phys block: compacted mem slot allocation (2304 phys slots)
        int tid = threadIdx.x;
        for (int e = tid; e < 4096; e += 256) {
            int v = e, p;
            for (;;) {
                int d = v >> 9, j = v & 511;
                if (d == 0)  { p = j; break; }
                if (j < 256) { p = 256 + d * 256 + j; break; }
                v = recall_idx[(d - 1) * 256 + (j - 256)];
            }
            physL[e] = p;
        }
        __syncthreads();
        int* pa = (int*)(ws + PHYSA_OFF);
        for (int e = tid; e < 2048; e += 256) {
            int d = e >> 8, t = e & 255;
            int a = 2 * (t & 127) + (t >> 7);
            pa[2 * e]     = 2 * physL[d * 512 + 2 * a];       // interleaved addr
            pa[2 * e + 1] = 2 * physL[d * 512 + 2 * a + 1];
        }
        int* pr = (int*)(ws + PHYSR_OFF);
        for (int e = tid; e < 2048; e += 256)
            pr[e] = 2 * physL[recall_idx[e]];                 // interleaved addr
        int* po = (int*)(ws + PHYSO2_OFF);
        for (int e = tid; e < 3072; e += 256) {
            int tt = e / 12; int r = e - 12 * tt; int i = r >> 2; int k = r & 3;
            int a = tt + 256 * i;
            int tl2 = a >> 1, th2 = a & 1;
            int pos = tl2 + 1536 * th2 + 384 * k;
            po[e] = (pos < 2048) ? 2 * physL[out_mem_idx[pos]]
                                 : MB0 + 2 * (pos - 2048);    // absolute lds addr
        }
    }
}

__device__ __forceinline__ float actf(float x, float c, float ic) {
    const float is2 = 0.70710678118654752f;
    float tt = 0.78539816339744831f * ic;
    float y0 = is2 * ic;
    float y1 = (is2 - 1.0f) * ic;
    float mid = ic * (is2 - __cosf(0.78539816339744831f + c * x));
    return x > tt ? (y0 + (x - tt)) : (x < -tt ? y1 : mid);
}

// ---------------- main kernel: 2 rows per block, row-interleaved LDS ---------------
__launch_bounds__(256, 4)
__global__ void sponge_kernel(const float* __restrict__ X,
                              const float* __restrict__ scales,
                              const float* __restrict__ ws,
                              float* __restrict__ out) {
    __shared__ float L[8704];            // 34816 B -> 4 blocks/CU
    const int t = threadIdx.x;
    const int rowA = blockIdx.x * 2;

    const float4* bf01  = (const float4*)(ws + BF01_OFF);
    const float4* bff   = (const float4*)(ws + BFF_OFF);
    const float4* act4  = (const float4*)(ws + ACT4_OFF);
    const int2* physA  = (const int2*)(ws + PHYSA_OFF);
    const int*  physr  = (const int*)(ws + PHYSR_OFF);
    const int*  physo2 = (const int*)(ws + PHYSO2_OFF);

    const int tl = t & 127, th = t >> 7;
    const int b  = tl + th * 512;        // holdings {b+128m}; quad a = 2tl+th
    const int a  = 2 * tl + th;
    // bit-permutation layout A: A0=p0, A1..A4=p2..p5, A5=p1, A6..A9=p6..p9
    const int Wb = 2 * (tl & 15) + 32 * th + 64 * (tl >> 4);    // A(2a)
    const int Rb = (tl & 1) + 2 * ((tl >> 2) & 15) + 32 * ((tl >> 1) & 1)
                 + 64 * (tl >> 6) + 512 * th;                   // A(b)
    const int WI = 2 * Wb;               // b128 write base (interleaved)
    const int RI = 2 * Rb;               // b64 read base, +256m
    const int u  = t - 128;

    float hA0, hA1, hA2, hA3, hB0, hB1, hB2, hB3;
    {
        const float* Xr0 = X + (size_t)rowA * 1024;
        const float* Xr1 = Xr0 + 1024;
        float s0 = scales[b],       s1 = scales[b + 128];
        float s2 = scales[b + 256], s3 = scales[b + 384];
        hA0 = Xr0[b] * s0; hA1 = Xr0[b + 128] * s1;
        hA2 = Xr0[b + 256] * s2; hA3 = Xr0[b + 384] * s3;
        hB0 = Xr1[b] * s0; hB1 = Xr1[b + 128] * s1;
        hB2 = Xr1[b + 256] * s2; hB3 = Xr1[b + 384] * s3;
    }

    int woff = MB0, roff = MB1;
    const float4* ft = (const float4*)(ws + FTAB_OFF) + 2 * t;

#define DQUAD(cA, cB, i0, i1, i2, i3, F0, F1, F2, F3)                    \
    { float g0 =  (cA).x * (i0) + (cA).y * (i2);                         \
      float g2 = -(cA).y * (i0) + (cA).x * (i2);                         \
      float g1 =  (cA).z * (i1) + (cA).w * (i3);                         \
      float g3 = -(cA).w * (i1) + (cA).z * (i3);                         \
      F0 =  (cB).x * g0 + (cB).y * g1;                                   \
      F2 = -(cB).y * g0 + (cB).x * g1;                                   \
      F1 =  (cB).z * g2 + (cB).w * g3;                                   \
      F3 = -(cB).w * g2 + (cB).z * g3; }

    for (int d = 0; d < DEPTH; ++d) {
        for (int g = 0; g < 5; ++g) {
            float4 csA = ft[0], csB = ft[1]; ft += 512;
            float fA0, fA1, fA2, fA3, fB0, fB1, fB2, fB3;
            DQUAD(csA, csB, hA0, hA1, hA2, hA3, fA0, fA1, fA2, fA3);
            DQUAD(csA, csB, hB0, hB1, hB2, hB3, fB0, fB1, fB2, fB3);
            if (g < 4) {
                // logical {2a,2a+1} both rows -> contiguous b128; {2a+512,2a+513} at +1024
                *(float4*)(L + woff + WI)        = make_float4(fA0, fB0, fA1, fB1);
                *(float4*)(L + woff + WI + 1024) = make_float4(fA2, fB2, fA3, fB3);
                { int tmp = woff; woff = roff; roff = tmp; }
                __syncthreads();
                float2 e0 = *(const float2*)(L + roff + RI);
                float2 e1 = *(const float2*)(L + roff + RI + 256);
                float2 e2 = *(const float2*)(L + roff + RI + 512);
                float2 e3 = *(const float2*)(L + roff + RI + 768);
                hA0 = e0.x; hB0 = e0.y; hA1 = e1.x; hB1 = e1.y;
                hA2 = e2.x; hB2 = e2.y; hA3 = e3.x; hB3 = e3.y;
            } else {
                // mem half (2a,2a+1): b64 scatter into interleaved memb
                int2 pm = physA[d * 256 + t];
                *(float2*)(L + pm.x) = make_float2(fA0, fB0);
                *(float2*)(L + pm.y) = make_float2(fA1, fB1);
                // sponge half -> natural interleaved Z at zpos {2a, 2a+1}: b128 at 4a
                *(float4*)(L + woff + 4 * a) = make_float4(fA2, fB2, fA3, fB3);
                { int tmp = woff; woff = roff; roff = tmp; }
                // prefetch before barrier (wave-aligned split)
                int r0 = 0, r1 = 0;
                float4 a0, a1, a2, a3;
                if (t < 128) {
                    int k0 = t >> 1;
                    a0 = act4[d * 256 + k0];
                    a1 = act4[d * 256 + k0 + 64];
                    a2 = act4[d * 256 + k0 + 128];
                    a3 = act4[d * 256 + k0 + 192];
                } else {
                    r0 = physr[d * 256 + u];
                    r1 = physr[d * 256 + u + 128];
                }
                __syncthreads();         // Z + mem scatter visible
                const float* Z = L + roff;
                if (t < 128) {
                    int k0 = t >> 1;
                    float sgn = (t & 1) ? -1.0f : 1.0f;
                    float2 z0 = *(const float2*)(Z + 2 * k0);
                    float2 z1 = *(const float2*)(Z + 2 * k0 + 128);
                    float2 z2 = *(const float2*)(Z + 2 * k0 + 256);
                    float2 z3 = *(const float2*)(Z + 2 * k0 + 384);
                    hA0 = actf(sgn * (z0.x + a0.x), a0.y, a0.z);
                    hB0 = actf(sgn * (z0.y + a0.x), a0.y, a0.z);
                    hA1 = actf(sgn * (z1.x + a1.x), a1.y, a1.z);
                    hB1 = actf(sgn * (z1.y + a1.x), a1.y, a1.z);
                    hA2 = actf(sgn * (z2.x + a2.x), a2.y, a2.z);
                    hB2 = actf(sgn * (z2.y + a2.x), a2.y, a2.z);
                    hA3 = actf(sgn * (z3.x + a3.x), a3.y, a3.z);
                    hB3 = actf(sgn * (z3.y + a3.x), a3.y, a3.z);
                } else {
                    // keep: zpos {256+u, 384+u}
                    float2 k0v = *(const float2*)(Z + 512 + 2 * u);
                    float2 k1v = *(const float2*)(Z + 768 + 2 * u);
                    float2 rc0 = *(const float2*)(L + r0);
                    float2 rc1 = *(const float2*)(L + r1);
                    hA0 = k0v.x; hB0 = k0v.y;
                    hA1 = k1v.x; hB1 = k1v.y;
                    hA2 = rc0.x; hB2 = rc0.y;
                    hA3 = rc1.x; hB3 = rc1.y;
                }
            }
        }
    }

    // ---- stage sponge into natural interleaved layout at MB0 (buf0 is free: woff==MB0) ----
    *(float2*)(L + MB0 + 2 * b)       = make_float2(hA0, hB0);
    *(float2*)(L + MB0 + 2 * b + 256) = make_float2(hA1, hB1);
    *(float2*)(L + MB0 + 2 * b + 512) = make_float2(hA2, hB2);
    *(float2*)(L + MB0 + 2 * b + 768) = make_float2(hA3, hB3);
    __syncthreads();

    // ---- gather pre: 12 b64 loads (absolute addrs), both rows at once ----
    float2 w0, w1, w2, w3, w4, w5, w6, w7, w8, w9, w10, w11;
    {
        int4 pg = ((const int4*)(physo2 + t * 12))[0];
        w0 = *(const float2*)(L + pg.x); w1 = *(const float2*)(L + pg.y);
        w2 = *(const float2*)(L + pg.z); w3 = *(const float2*)(L + pg.w);
        pg = ((const int4*)(physo2 + t * 12))[1];
        w4 = *(const float2*)(L + pg.x); w5 = *(const float2*)(L + pg.y);
        w6 = *(const float2*)(L + pg.z); w7 = *(const float2*)(L + pg.w);
        pg = ((const int4*)(physo2 + t * 12))[2];
        w8 = *(const float2*)(L + pg.x); w9 = *(const float2*)(L + pg.y);
        w10 = *(const float2*)(L + pg.z); w11 = *(const float2*)(L + pg.w);
    }
    __syncthreads();                     // all reads done before overwrite

    // ---- fused stages (0,1) in registers; final buffer = interleaved [0,6144) ----
#define BF01_STEP(i, q0, q1, q2, q3)                                                \
    {                                                                               \
        float4 c01 = bf01[(t * 3 + (i)) * 2];                                       \
        float4 c23 = bf01[(t * 3 + (i)) * 2 + 1];                                   \
        float yA0, yA1, yA2, yA3, yB0, yB1, yB2, yB3;                               \
        DQUAD(c01, c23, q0.x, q1.x, q2.x, q3.x, yA0, yA1, yA2, yA3);                \
        DQUAD(c01, c23, q0.y, q1.y, q2.y, q3.y, yB0, yB1, yB2, yB3);                \
        *(float4*)(L + 4 * t + 1024 * (i))        = make_float4(yA0, yB0, yA1, yB1);\
        *(float4*)(L + 4 * t + 1024 * (i) + 3072) = make_float4(yA2, yB2, yA3, yB3);\
    }
    BF01_STEP(0, w0, w1, w2, w3)
    BF01_STEP(1, w4, w5, w6, w7)
    BF01_STEP(2, w8, w9, w10, w11)
#undef BF01_STEP
    __syncthreads();

    // ---- fused pruned double-stages (2,3) (4,5) (6,7) (8,9) ----
#pragma unroll
    for (int f = 0; f < 4; ++f) {
        int P;
        if (f == 0) P = 3 * t;
        else { const int k = 8 - 2 * f;
               P = ((t >> (2 * f)) * (768 >> k)) + (t & ((256 >> k) - 1)); }
        int base = 2 * ((P >> 1) + (P & 1) * 1536);
        float4 csS = bff[(f * 256 + t) * 2];
        float4 csT = bff[(f * 256 + t) * 2 + 1];
        float2 x1p = *(const float2*)(L + base);
        float2 x1q = *(const float2*)(L + base + 768);
        float2 x2p = *(const float2*)(L + base + 1536);
        float2 x2q = *(const float2*)(L + base + 2304);
        float o1P =  csS.x * x1p.x + csS.y * x2p.x;
        float o2P = -csS.y * x1p.x + csS.x * x2p.x;
        float o1Q =  csS.z * x1q.x + csS.w * x2q.x;
        float o2Q = -csS.w * x1q.x + csS.z * x2q.x;
        float yA0 =  csT.x * o1P + csT.y * o1Q;
        float yA2 = -csT.y * o1P + csT.x * o1Q;
        float yA1 =  csT.z * o2P + csT.w * o2Q;
        float yA3 = -csT.w * o2P + csT.z * o2Q;
        o1P =  csS.x * x1p.y + csS.y * x2p.y;
        o2P = -csS.y * x1p.y + csS.x * x2p.y;
        o1Q =  csS.z * x1q.y + csS.w * x2q.y;
        o2Q = -csS.w * x1q.y + csS.z * x2q.y;
        float yB0 =  csT.x * o1P + csT.y * o1Q;
        float yB2 = -csT.y * o1P + csT.x * o1Q;
        float yB1 =  csT.z * o2P + csT.w * o2Q;
        float yB3 = -csT.w * o2P + csT.z * o2Q;
        __syncthreads();
        *(float4*)(L + 4 * P)        = make_float4(yA0, yB0, yA1, yB1);
        *(float4*)(L + 4 * P + 3072) = make_float4(yA2, yB2, yA3, yB3);
        __syncthreads();
    }

    // ---- fused (10,11) + output store, both rows ----
    {
        int base = 2 * ((t >> 1) + (t & 1) * 1536);
        float4 csS = bff[(4 * 256 + t) * 2];
        float4 csT = bff[(4 * 256 + t) * 2 + 1];
        float2 x1p = *(const float2*)(L + base);
        float2 x1q = *(const float2*)(L + base + 768);
        float2 x2p = *(const float2*)(L + base + 1536);
        float2 x2q = *(const float2*)(L + base + 2304);
        float o1P =  csS.x * x1p.x + csS.y * x2p.x;
        float o2P = -csS.y * x1p.x + csS.x * x2p.x;
        float o1Q =  csS.z * x1q.x + csS.w * x2q.x;
        float o2Q = -csS.w * x1q.x + csS.z * x2q.x;
        *(float2*)(out + (size_t)rowA * 512 + 2 * t) =
            make_float2(csT.x * o1P + csT.y * o1Q, csT.z * o2P + csT.w * o2Q);
        o1P =  csS.x * x1p.y + csS.y * x2p.y;
        o2P = -csS.y * x1p.y + csS.x * x2p.y;
        o1Q =  csS.z * x1q.y + csS.w * x2q.y;
        o2Q = -csS.w * x1q.y + csS.z * x2q.y;
        *(float2*)(out + (size_t)(rowA + 1) * 512 + 2 * t) =
            make_float2(csT.x * o1P + csT.y * o1Q, csT.z * o2P + csT.w * o2Q);
    }
#undef DQUAD
}

extern "C" void kernel_launch(void* const* d_in, const int* in_sizes, int n_in,
                              void* d_out, int out_size, void* d_ws, size_t ws_size,
                              hipStream_t stream) {
    const float* X          = (const float*)d_in[0];
    const float* scales     = (const float*)d_in[1];
    const float* angles     = (const float*)d_in[2];
    const float* act_bias   = (const float*)d_in[3];
    // d_in[4] act_activation — unused by the reference
    const float* act_curv   = (const float*)d_in[5];
    const float* bf_angles  = (const float*)d_in[6];
    // d_in[7] shuffle_perm — structural perfect shuffle, hardcoded
    const int*   recall_idx  = (const int*)d_in[8];
    const int*   out_mem_idx = (const int*)d_in[9];
    // d_in[10] bf_perm — structural perfect shuffle, hardcoded

    float* ws = (float*)d_ws;   // 462848 bytes used

    setup_kernel<<<201, 256, 0, stream>>>(angles, bf_angles, act_bias, act_curv,
                                          recall_idx, out_mem_idx, ws);
    sponge_kernel<<<NB / 2, 256, 0, stream>>>(X, scales, ws, (float*)d_out);
}